// Round 20
// baseline (319.712 us; speedup 1.0000x reference)
//
#include <hip/hip_runtime.h>
#include <cmath>

typedef _Float16 half_t;
typedef _Float16 half8 __attribute__((ext_vector_type(8)));
typedef _Float16 half4 __attribute__((ext_vector_type(4)));
typedef float floatx4 __attribute__((ext_vector_type(4)));

__device__ __forceinline__ float lrelu_f(float v) { return v >= 0.f ? v : 0.1f * v; }

// ---------------------------------------------------------------------------
// Weight pack helper: OIHW fp32 -> f16 [tap][cinblk][co_total][ci(32)]
// ---------------------------------------------------------------------------
template <int CIN, int COTOT>
__device__ __forceinline__ void pack_one(const float* __restrict__ w,
                                         half_t* __restrict__ o,
                                         int co_off, int co_n, int i)
{
    constexpr int NCB = (CIN + 31) / 32;
    int ci = i & 31;
    int t = i >> 5;
    int col = t % co_n; t /= co_n;
    int cb = t % NCB;
    int tap = t / NCB;
    int cg = cb * 32 + ci;
    float v = (cg < CIN) ? w[((long)col * CIN + cg) * 9 + tap] : 0.f;
    o[(((long)tap * NCB + cb) * COTOT + co_off + col) * 32 + ci] = (half_t)v;
}

// All 9 weight tensors packed in ONE launch (segment by linear index).
__global__ __launch_bounds__(256) void prep_w_all(
    const float* __restrict__ qk, const float* __restrict__ ev,
    const float* __restrict__ so, const float* __restrict__ aw,
    const float* __restrict__ vp, const float* __restrict__ op,
    const float* __restrict__ ffw, const float* __restrict__ f1,
    const float* __restrict__ f2,
    half_t* wq, half_t* wv, half_t* wsoaw, half_t* wvp2, half_t* wop2,
    half_t* wff2, half_t* wffn1, half_t* wffn2)
{
    int i = blockIdx.x * 256 + threadIdx.x;
    constexpr int C0 = 110592;            // qk  (CIN100,NCB4,96)
    constexpr int C1 = C0 + 82944;        // ev  (96,3,96)
    constexpr int C2 = C1 + 82944;        // so  -> wsoaw[0:96)
    constexpr int C3 = C2 + 41472;        // aw  -> wsoaw[96:144)
    constexpr int C4 = C3 + 9216;         // vp
    constexpr int C5 = C4 + 9216;         // op
    constexpr int C6 = C5 + 9216;         // ff
    constexpr int C7 = C6 + 18432;        // ffn1 (64,2,32)
    constexpr int C8 = C7 + 9216;         // ffn2
    if (i < C0)      pack_one<100, 96>(qk, wq, 0, 96, i);
    else if (i < C1) pack_one<96, 96>(ev, wv, 0, 96, i - C0);
    else if (i < C2) pack_one<96, 144>(so, wsoaw, 0, 96, i - C1);
    else if (i < C3) pack_one<96, 144>(aw, wsoaw, 96, 48, i - C2);
    else if (i < C4) pack_one<32, 32>(vp, wvp2, 0, 32, i - C3);
    else if (i < C5) pack_one<32, 32>(op, wop2, 0, 32, i - C4);
    else if (i < C6) pack_one<32, 32>(ffw, wff2, 0, 32, i - C5);
    else if (i < C7) pack_one<64, 32>(f1, wffn1, 0, 32, i - C6);
    else if (i < C8) pack_one<32, 32>(f2, wffn2, 0, 32, i - C7);
}

// ---------------------------------------------------------------------------
// copy_cl: pure coalesced copies (no gathers). 4 threads/pixel, half8 stores.
// ---------------------------------------------------------------------------
__global__ __launch_bounds__(256) void copy_cl_kernel(
    const float* __restrict__ frame, const float* __restrict__ srcframe,
    const float* __restrict__ ff, const float* __restrict__ fb,
    half_t* __restrict__ qin, half_t* __restrict__ fcl,
    half_t* __restrict__ o3rec, int H, int W)
{
    const int HW = H * W;
    const int p = threadIdx.x >> 2, sub = threadIdx.x & 3;
    const int q = blockIdx.x * 64 + p;
    const int b = blockIdx.y;
    const long fbase = (long)b * 96 * HW;
    const long rq = ((long)b * HW + q) * 112;
    const long rf = ((long)b * HW + q) * 96;
    const long r3 = ((long)b * HW + q) * 64;

    half8 c0, c2;
    #pragma unroll
    for (int d = 0; d < 8; ++d) {
        c0[d] = (half_t)frame[fbase + (long)(sub * 8 + d) * HW + q];
        c2[d] = (half_t)frame[fbase + (long)(64 + sub * 8 + d) * HW + q];
    }
    *(half8*)&fcl[rf + sub * 8] = c0;
    *(half8*)&fcl[rf + 64 + sub * 8] = c2;

    half8 fv, sv;
    #pragma unroll
    for (int d = 0; d < 8; ++d) {
        long off = fbase + (long)(32 + sub * 8 + d) * HW + q;
        fv[d] = (half_t)frame[off];
        sv[d] = (half_t)srcframe[off];
    }
    *(half8*)&qin[rq + 32 + sub * 8] = fv;
    *(half8*)&fcl[rf + 32 + sub * 8] = fv;
    *(half8*)&o3rec[r3 + 32 + sub * 8] = sv;

    if (sub == 0) {
        half8 fl = {};
        fl[0] = (half_t)ff[((long)(b * 2 + 1) * 2 + 0) * HW + q];
        fl[1] = (half_t)ff[((long)(b * 2 + 1) * 2 + 1) * HW + q];
        fl[2] = (half_t)fb[((long)(b * 2 + 0) * 2 + 0) * HW + q];
        fl[3] = (half_t)fb[((long)(b * 2 + 0) * 2 + 1) * HW + q];
        *(half8*)&qin[rq + 96] = fl;
    } else if (sub == 1) {
        half8 z = {};
        *(half8*)&qin[rq + 104] = z;
    }
}

// ---------------------------------------------------------------------------
// warp_cl: bilinear warps reading CL fcl records (16B half8 per corner-chunk).
// ---------------------------------------------------------------------------
__global__ __launch_bounds__(256) void warp_cl_kernel(
    const half_t* __restrict__ fcl, const float* __restrict__ ff,
    const float* __restrict__ fb, half_t* __restrict__ qin, int H, int W)
{
    const int HW = H * W;
    const int p = threadIdx.x >> 2, sub = threadIdx.x & 3;
    const int q = blockIdx.x * 64 + p;
    const int b = blockIdx.y;
    const int x = q % W, y = q / W;
    const long rq = ((long)b * HW + q) * 112;
    const half_t* fc = fcl + (long)b * HW * 96;

    const float fb0x = fb[((long)(b * 2 + 0) * 2 + 0) * HW + q];
    const float fb0y = fb[((long)(b * 2 + 0) * 2 + 1) * HW + q];
    const float ff1x = ff[((long)(b * 2 + 1) * 2 + 0) * HW + q];
    const float ff1y = ff[((long)(b * 2 + 1) * 2 + 1) * HW + q];

    #pragma unroll
    for (int t = 0; t < 2; ++t) {
        const float fx = t ? ff1x : fb0x;
        const float fy = t ? ff1y : fb0y;
        const int coff = t ? 64 : 0;
        float gx = (float)x + fx, gy = (float)y + fy;
        float x0f = floorf(gx), y0f = floorf(gy);
        float wx = gx - x0f, wy = gy - y0f;
        int x0 = min(max((int)x0f, 0), W - 1);
        int x1 = min(max((int)x0f + 1, 0), W - 1);
        int y0 = min(max((int)y0f, 0), H - 1);
        int y1 = min(max((int)y0f + 1, 0), H - 1);
        float w00 = (1.f - wx) * (1.f - wy), w10 = wx * (1.f - wy);
        float w01 = (1.f - wx) * wy, w11 = wx * wy;

        half8 v00 = *(const half8*)&fc[(long)(y0 * W + x0) * 96 + coff + sub * 8];
        half8 v10 = *(const half8*)&fc[(long)(y0 * W + x1) * 96 + coff + sub * 8];
        half8 v01 = *(const half8*)&fc[(long)(y1 * W + x0) * 96 + coff + sub * 8];
        half8 v11 = *(const half8*)&fc[(long)(y1 * W + x1) * 96 + coff + sub * 8];

        half8 st;
        #pragma unroll
        for (int d = 0; d < 8; ++d) {
            float v = (float)v00[d] * w00 + (float)v10[d] * w10 +
                      (float)v01[d] * w01 + (float)v11[d] * w11;
            st[d] = (half_t)v;
        }
        *(half8*)&qin[rq + coff + sub * 8] = st;
    }
}

// ---------------------------------------------------------------------------
// Channel-last implicit-GEMM 3x3 conv on MFMA f16 — v8: ALL cin-blocks of
// this z-slice's weights staged to LDS ONCE in the prologue (fits: CON=48 ->
// <=115KB). Steady-state loop stages only 20.7KB acts between barriers
// (-58% critical-path bytes vs R18). Reg prefetch of next-cb acts retained.
// ---------------------------------------------------------------------------
template <int CREC, int CIN, int COUT, int DIL, bool LRELU, int RESID_MODE,
          int OUTC, int SPLIT, bool OUT_TGROUP, int RESREC, int CON>
__global__ __launch_bounds__(512, 2) void conv3x3_cl(
    const half_t* __restrict__ in, long in_stride,
    const half_t* __restrict__ w16,
    const float* __restrict__ bias0, const float* __restrict__ bias1,
    const void* __restrict__ resid, long resid_stride,
    half_t* __restrict__ out, long out_stride, int H, int W)
{
    constexpr int NCB = (CIN + 31) / 32;
    constexpr int S = 16 + 2 * DIL;
    constexpr int NF = CON / 16;                   // co-frags per block
    constexpr int COPAD = CON + 2;                 // +2 chunks -> 8-bank stagger
    constexpr int NLD = S * S * 4;                 // act half8 chunks / cb
    constexpr int NITEM = (NLD + 511) / 512;
    constexpr int WCH = 9 * 4 * COPAD;             // weight chunks / cb
    __shared__ half_t sa[NLD * 8];
    __shared__ half_t sw[NCB * WCH * 8];           // ALL cbs resident

    const int n = blockIdx.y;
    const int cobase = blockIdx.z * CON;
    const int tile = blockIdx.x;
    const int tx = tile & 15, ty = tile >> 4;      // W==256 -> 16 tiles/row
    const int tid = threadIdx.x;
    const int wv = tid >> 6, lane = tid & 63;
    const int cl = lane & 15, jk = lane >> 4;

    floatx4 acc[2][NF] = {};

    const int gy0 = ty * 16 - DIL, gx0 = tx * 16 - DIL;
    const int HWl = H * W;
    const half_t* ib = in + (long)n * in_stride;

    // act staging geometry (loop-invariant)
    int pxv[NITEM], gofs[NITEM];
    bool inb[NITEM];
    #pragma unroll
    for (int k = 0; k < NITEM; ++k) {
        int i = tid + k * 512;
        int pix = i >> 2;
        int sy = pix / S, sx = pix - sy * S;
        int gy = gy0 + sy, gx = gx0 + sx;
        pxv[k] = pix;
        inb[k] = (i < NLD) && gy >= 0 && gy < H && gx >= 0 && gx < W;
        gofs[k] = gy * W + gx;
    }

    half8 ra[NITEM];
    auto LOADA = [&](int cb) {
        #pragma unroll
        for (int k = 0; k < NITEM; ++k) {
            int i = tid + k * 512;
            int c_g = cb * 4 + (i & 3);
            half8 v = {};
            if (inb[k] && (c_g * 8 + 8 <= CREC))
                v = *(const half8*)&ib[(long)gofs[k] * CREC + c_g * 8];
            ra[k] = v;
        }
    };
    auto WRITEA = [&]() {
        #pragma unroll
        for (int k = 0; k < NITEM; ++k) {
            int i = tid + k * 512;
            if (i < NLD) {
                int pix = pxv[k], chunk = i & 3;
                *(half8*)&sa[((pix << 2) + (chunk ^ ((pix >> 1) & 3))) << 3] = ra[k];
            }
        }
    };

    // ---- prologue: all weights once + first act block ----
    for (int j = tid; j < NCB * WCH; j += 512) {
        int cb = j / WCH;
        int r = j - cb * WCH;
        int tj = r / COPAD;                        // tap*4 + jk
        int co = r - tj * COPAD;
        half8 v = {};
        if (co < CON) {
            int tap = tj >> 2, jj = tj & 3;
            v = *(const half8*)&w16[(((long)tap * NCB + cb) * COUT + cobase + co) * 32 + jj * 8];
        }
        *(half8*)&sw[j * 8] = v;
    }
    LOADA(0);
    WRITEA();
    __syncthreads();

    for (int cb = 0; cb < NCB; ++cb) {
        if (cb + 1 < NCB) LOADA(cb + 1);           // hidden by MFMA

        const half_t* swb = sw + (long)cb * WCH * 8;
        #pragma unroll
        for (int tap = 0; tap < 9; ++tap) {
            const int ky = tap / 3, kx = tap % 3;
            half8 af[2];
            #pragma unroll
            for (int m = 0; m < 2; ++m) {
                int pix = (wv * 2 + m + ky * DIL) * S + kx * DIL + cl;
                af[m] = *(const half8*)&sa[((pix << 2) + (jk ^ ((pix >> 1) & 3))) << 3];
            }
            const int wbase = ((tap << 2) | jk) * COPAD + cl;
            #pragma unroll
            for (int nn = 0; nn < NF; ++nn) {
                half8 bf = *(const half8*)&swb[(wbase + nn * 16) * 8];
                acc[0][nn] = __builtin_amdgcn_mfma_f32_16x16x32_f16(af[0], bf, acc[0][nn], 0, 0, 0);
                acc[1][nn] = __builtin_amdgcn_mfma_f32_16x16x32_f16(af[1], bf, acc[1][nn], 0, 0, 0);
            }
        }

        if (cb + 1 < NCB) {
            __syncthreads();               // all waves done reading sa
            WRITEA();
            __syncthreads();               // new cb visible
        }
    }

    // ---- epilogue. C map: co = cobase + nn*16 + cl; px = jk*4 + i ----
    const int x0 = tx * 16 + jk * 4;
    #pragma unroll
    for (int m = 0; m < 2; ++m) {
        const int yy = ty * 16 + wv * 2 + m;
        #pragma unroll
        for (int nn = 0; nn < NF; ++nn) {
            const int co = cobase + nn * 16 + cl;
            float bv = (co < SPLIT) ? bias0[co] : bias1[co - SPLIT];
            float r[4];
            #pragma unroll
            for (int i = 0; i < 4; ++i) r[i] = acc[m][nn][i] + bv;
            if constexpr (RESID_MODE == 1) {
                const float* rp = (const float*)resid + (long)n * resid_stride +
                                  (long)co * HWl + (long)yy * W + x0;
                float4 rv = *(const float4*)rp;
                r[0] += rv.x; r[1] += rv.y; r[2] += rv.z; r[3] += rv.w;
            } else if constexpr (RESID_MODE == 3) {
                const half_t* rp = (const half_t*)resid +
                                   ((long)n * HWl + (long)yy * W + x0) * RESREC + co;
                #pragma unroll
                for (int i = 0; i < 4; ++i) r[i] += (float)rp[i * RESREC];
            }
            if (LRELU) {
                #pragma unroll
                for (int i = 0; i < 4; ++i) r[i] = lrelu_f(r[i]);
            }
            if constexpr (OUT_TGROUP) {
                long base = ((long)(n * 3 + (co >> 5)) * HWl + (long)yy * W + x0) * 32 + (co & 31);
                #pragma unroll
                for (int i = 0; i < 4; ++i) out[base + i * 32] = (half_t)r[i];
            } else {
                long base = (long)n * out_stride + ((long)yy * W + x0) * OUTC + co;
                #pragma unroll
                for (int i = 0; i < 4; ++i) out[base + i * OUTC] = (half_t)r[i];
            }
        }
    }
}

// ---------------------------------------------------------------------------
// Fused deformable attention v3 (unchanged): one head per thread.
// ---------------------------------------------------------------------------
__global__ __launch_bounds__(256) void deform_v3(
    const half_t* __restrict__ v_cl, const half_t* __restrict__ offaw,
    const float* __restrict__ ff, const float* __restrict__ fb,
    half_t* __restrict__ out1, int H, int W)
{
    const int HW = H * W;
    const int bid = blockIdx.x;                   // 1024 tiles (8x8 px)
    const int swz = (bid & 7) * 128 + (bid >> 3); // bijective XCD swizzle
    const int tx = swz & 31, ty = swz >> 5;       // 32x32 tile grid
    const int b = blockIdx.y;
    const int p = threadIdx.x >> 2;               // pixel in tile (0..63)
    const int m = threadIdx.x & 3;                // head
    const int x = tx * 8 + (p & 7), y = ty * 8 + (p >> 3);
    const int q = y * W + x;

    const half_t* rec = &offaw[((long)b * HW + q) * 144];
    half8 offv[3];
    #pragma unroll
    for (int i = 0; i < 3; ++i) offv[i] = *(const half8*)&rec[m * 24 + i * 8];
    half4 awv[3];
    #pragma unroll
    for (int i = 0; i < 3; ++i) awv[i] = *(const half4*)&rec[96 + m * 12 + i * 4];

    float fbx = fb[((long)(b * 2 + 0) * 2 + 0) * HW + q];
    float fby = fb[((long)(b * 2 + 0) * 2 + 1) * HW + q];
    float ffx = ff[((long)(b * 2 + 1) * 2 + 0) * HW + q];
    float ffy = ff[((long)(b * 2 + 1) * 2 + 1) * HW + q];

    float a[12], mx = -1e30f;
    #pragma unroll
    for (int i = 0; i < 12; ++i) {
        a[i] = (float)awv[i >> 2][i & 3];
        mx = fmaxf(mx, a[i]);
    }
    float s = 0.f;
    #pragma unroll
    for (int i = 0; i < 12; ++i) { a[i] = expf(a[i] - mx); s += a[i]; }
    float inv = 1.f / s;

    float o[8] = {0, 0, 0, 0, 0, 0, 0, 0};
    #pragma unroll
    for (int l = 0; l < 3; ++l) {
        float fx = (l == 0) ? fbx : (l == 2) ? ffx : 0.f;
        float fy = (l == 0) ? fby : (l == 2) ? ffy : 0.f;
        const half_t* img = v_cl + (long)(b * 3 + l) * HW * 32 + m * 8;
        #pragma unroll
        for (int pp = 0; pp < 4; ++pp) {
            int oc = (l * 4 + pp) * 2;
            float gx = (float)x + (float)offv[oc >> 3][oc & 7] + fx;
            float gy = (float)y + (float)offv[(oc + 1) >> 3][(oc + 1) & 7] + fy;
            float wgt = a[l * 4 + pp] * inv;
            float x0f = floorf(gx), y0f = floorf(gy);
            float wx = gx - x0f, wy = gy - y0f;
            int x0 = (int)x0f, y0 = (int)y0f;
            #pragma unroll
            for (int t_ = 0; t_ < 4; ++t_) {
                int xi = x0 + (t_ & 1), yi = y0 + (t_ >> 1);
                float wt = ((t_ & 1) ? wx : 1.f - wx) *
                           ((t_ >> 1) ? wy : 1.f - wy) * wgt;
                if (xi >= 0 && xi < W && yi >= 0 && yi < H) {
                    const half8 vv = *(const half8*)&img[(long)(yi * W + xi) * 32];
                    #pragma unroll
                    for (int d = 0; d < 8; ++d) o[d] = fmaf(wt, (float)vv[d], o[d]);
                }
            }
        }
    }
    half8 st;
    #pragma unroll
    for (int d = 0; d < 8; ++d) st[d] = (half_t)o[d];
    *(half8*)&out1[((long)b * HW + q) * 32 + m * 8] = st;
}

// ---------------------------------------------------------------------------
// 1x1 conv (32->32) + lrelu, CL f16 in, fp32 planar out (final)
// ---------------------------------------------------------------------------
__global__ __launch_bounds__(256) void conv1x1_f16(
    const half_t* __restrict__ in, const float* __restrict__ w,
    const float* __restrict__ bias, float* __restrict__ out, int HW)
{
    int q = blockIdx.x * 256 + threadIdx.x;
    if (q >= HW) return;
    long b = blockIdx.y;
    const half8* ip = (const half8*)&in[((long)b * HW + q) * 32];
    half8 vv[4];
    #pragma unroll
    for (int i = 0; i < 4; ++i) vv[i] = ip[i];
    float v[32];
    #pragma unroll
    for (int ci = 0; ci < 32; ++ci) v[ci] = (float)vv[ci >> 3][ci & 7];
    float* ob = out + b * 32 * HW;
    #pragma unroll
    for (int co = 0; co < 32; ++co) {
        float acc = bias[co];
        #pragma unroll
        for (int ci = 0; ci < 32; ++ci) acc = fmaf(w[co * 32 + ci], v[ci], acc);
        ob[(long)co * HW + q] = lrelu_f(acc);
    }
}

// ---------------------------------------------------------------------------
extern "C" void kernel_launch(void* const* d_in, const int* in_sizes, int n_in,
                              void* d_out, int out_size, void* d_ws, size_t ws_size,
                              hipStream_t stream)
{
    (void)in_sizes; (void)n_in; (void)out_size; (void)ws_size;
    const int H = 256, W = 256, HW = H * W, B = 2;

    const float* frame    = (const float*)d_in[0];
    const float* srcframe = (const float*)d_in[1];
    const float* ff       = (const float*)d_in[2];
    const float* fb       = (const float*)d_in[3];
    const float* emb_qk_w = (const float*)d_in[4];
    const float* emb_qk_b = (const float*)d_in[5];
    const float* emb_v_w  = (const float*)d_in[6];
    const float* emb_v_b  = (const float*)d_in[7];
    const float* so_w     = (const float*)d_in[8];
    const float* so_b     = (const float*)d_in[9];
    const float* aw_w     = (const float*)d_in[10];
    const float* aw_b     = (const float*)d_in[11];
    const float* vp_w     = (const float*)d_in[12];
    const float* vp_b     = (const float*)d_in[13];
    const float* op_w     = (const float*)d_in[14];
    const float* op_b     = (const float*)d_in[15];
    const float* ff_w     = (const float*)d_in[16];
    const float* ff_b     = (const float*)d_in[17];
    const float* ffn1_w   = (const float*)d_in[18];
    const float* ffn1_b   = (const float*)d_in[19];
    const float* ffn2_w   = (const float*)d_in[20];
    const float* ffn2_b   = (const float*)d_in[21];
    const float* fus_w    = (const float*)d_in[22];
    const float* fus_b    = (const float*)d_in[23];

    half_t* hw = (half_t*)d_ws;
    half_t* q_in_cl = hw;                   // 2*HW*112
    half_t* fcl     = hw + 14680064L;       // 2*HW*96
    half_t* value_g = hw + 27262976L;       // 6*HW*32
    half_t* offaw   = hw + 14680064L;       // 2*HW*144 (alias fcl+value_g)
    half_t* query_c = hw + 39845888L;       // 2*HW*96
    half_t* v_cl    = hw + 52428800L;       // 6*HW*32
    half_t* out1    = hw + 65011712L;       // 2*HW*32
    half_t* out2    = hw + 69206016L;
    half_t* o3rec   = hw + 73400320L;       // 2*HW*64 (out3 | src1)
    half_t* ffnb    = hw + 81788928L;
    half_t* out4    = hw + 85983232L;
    half_t* wq      = hw + 90177536L;
    half_t* wv      = hw + 90288128L;
    half_t* wsoaw   = hw + 90371072L;
    half_t* wvp     = hw + 90495488L;
    half_t* wop     = hw + 90504704L;
    half_t* wff     = hw + 90513920L;
    half_t* wffn1   = hw + 90523136L;
    half_t* wffn2   = hw + 90541568L;

    dim3 blk(256);
    dim3 cblk(512);

    prep_w_all<<<(373248 + 255) / 256, blk, 0, stream>>>(
        emb_qk_w, emb_v_w, so_w, aw_w, vp_w, op_w, ff_w, ffn1_w, ffn2_w,
        wq, wv, wsoaw, wvp, wop, wff, wffn1, wffn2);

    copy_cl_kernel<<<dim3(HW / 64, B), blk, 0, stream>>>(frame, srcframe, ff, fb,
                                                         q_in_cl, fcl, o3rec, H, W);
    warp_cl_kernel<<<dim3(HW / 64, B), blk, 0, stream>>>(fcl, ff, fb, q_in_cl, H, W);

    // query = lrelu(conv(q_in, emb_qk))            CL 112 -> CL 96  (2x48 co)
    conv3x3_cl<112, 100, 96, 1, true, 0, 96, 96, false, 0, 48>
        <<<dim3(256, B, 2), cblk, 0, stream>>>(q_in_cl, (long)HW * 112, wq, emb_qk_b,
                                               nullptr, nullptr, 0, query_c,
                                               (long)HW * 96, H, W);
    // value = lrelu(conv(frame_cl, emb_v))         CL 96 -> [6][pix][32] (2x48)
    conv3x3_cl<96, 96, 96, 1, true, 0, 32, 96, true, 0, 48>
        <<<dim3(256, B, 2), cblk, 0, stream>>>(fcl, (long)HW * 96, wv, emb_v_b,
                                               nullptr, nullptr, 0, value_g, 0, H, W);
    // v = conv(value, vp) per image               CL 32 -> CL 32
    conv3x3_cl<32, 32, 32, 1, false, 0, 32, 32, false, 0, 32>
        <<<dim3(256, 6, 1), cblk, 0, stream>>>(value_g, (long)HW * 32, wvp, vp_b,
                                               nullptr, nullptr, 0, v_cl,
                                               (long)HW * 32, H, W);
    // off|aw = conv(query, so|aw)                  CL 96 -> CL 144 (3x48 co)
    conv3x3_cl<96, 96, 144, 1, false, 0, 144, 96, false, 0, 48>
        <<<dim3(256, B, 3), cblk, 0, stream>>>(query_c, (long)HW * 96, wsoaw, so_b,
                                               aw_b, nullptr, 0, offaw,
                                               (long)HW * 144, H, W);
    // out1 = deformable attention (one head per thread, 8x8 tiles)
    deform_v3<<<dim3(1024, B), blk, 0, stream>>>(v_cl, offaw, ff, fb, out1, H, W);
    // out2 = conv(out1, op)
    conv3x3_cl<32, 32, 32, 1, false, 0, 32, 32, false, 0, 32>
        <<<dim3(256, B, 1), cblk, 0, stream>>>(out1, (long)HW * 32, wop, op_b,
                                               nullptr, nullptr, 0, out2,
                                               (long)HW * 32, H, W);
    // out3 = conv(out2, ff_w) + frame[:,1]  -> o3rec lower half (record 64)
    conv3x3_cl<32, 32, 32, 1, false, 1, 64, 32, false, 0, 32>
        <<<dim3(256, B, 1), cblk, 0, stream>>>(out2, (long)HW * 32, wff, ff_b,
                                               nullptr, frame + 32L * HW, 96L * HW,
                                               o3rec, (long)HW * 64, H, W);
    // ffn = lrelu(conv_dil2(o3rec[out3|src1], ffn1))
    conv3x3_cl<64, 64, 32, 2, true, 0, 32, 32, false, 0, 32>
        <<<dim3(256, B, 1), cblk, 0, stream>>>(o3rec, (long)HW * 64, wffn1, ffn1_b,
                                               nullptr, nullptr, 0, ffnb,
                                               (long)HW * 32, H, W);
    // out4 = out3 + conv(ffn, ffn2)   (resid = o3rec CL stride 64)
    conv3x3_cl<32, 32, 32, 1, false, 3, 32, 32, false, 64, 32>
        <<<dim3(256, B, 1), cblk, 0, stream>>>(ffnb, (long)HW * 32, wffn2, ffn2_b,
                                               nullptr, o3rec, 0, out4,
                                               (long)HW * 32, H, W);
    // d_out = lrelu(conv1x1(out4, fus))
    conv1x1_f16<<<dim3(HW / 256, B), blk, 0, stream>>>(out4, fus_w, fus_b,
                                                       (float*)d_out, HW);
}

// Round 23
// 277.440 us; speedup vs baseline: 1.1524x; 1.1524x over previous
//
#include <hip/hip_runtime.h>
#include <cmath>

typedef _Float16 half_t;
typedef _Float16 half8 __attribute__((ext_vector_type(8)));
typedef _Float16 half4 __attribute__((ext_vector_type(4)));
typedef float floatx4 __attribute__((ext_vector_type(4)));

__device__ __forceinline__ float lrelu_f(float v) { return v >= 0.f ? v : 0.1f * v; }

// ---------------------------------------------------------------------------
// Weight pack helper: OIHW fp32 -> f16 [tap][cinblk][co_total][ci(32)]
// ---------------------------------------------------------------------------
template <int CIN, int COTOT>
__device__ __forceinline__ void pack_one(const float* __restrict__ w,
                                         half_t* __restrict__ o,
                                         int co_off, int co_n, int i)
{
    constexpr int NCB = (CIN + 31) / 32;
    int ci = i & 31;
    int t = i >> 5;
    int col = t % co_n; t /= co_n;
    int cb = t % NCB;
    int tap = t / NCB;
    int cg = cb * 32 + ci;
    float v = (cg < CIN) ? w[((long)col * CIN + cg) * 9 + tap] : 0.f;
    o[(((long)tap * NCB + cb) * COTOT + co_off + col) * 32 + ci] = (half_t)v;
}

// All 9 weight tensors packed in ONE launch (segment by linear index).
__global__ __launch_bounds__(256) void prep_w_all(
    const float* __restrict__ qk, const float* __restrict__ ev,
    const float* __restrict__ so, const float* __restrict__ aw,
    const float* __restrict__ vp, const float* __restrict__ op,
    const float* __restrict__ ffw, const float* __restrict__ f1,
    const float* __restrict__ f2,
    half_t* wq, half_t* wv, half_t* wsoaw, half_t* wvp2, half_t* wop2,
    half_t* wff2, half_t* wffn1, half_t* wffn2)
{
    int i = blockIdx.x * 256 + threadIdx.x;
    constexpr int C0 = 110592;            // qk  (CIN100,NCB4,96)
    constexpr int C1 = C0 + 82944;        // ev  (96,3,96)
    constexpr int C2 = C1 + 82944;        // so  -> wsoaw[0:96)
    constexpr int C3 = C2 + 41472;        // aw  -> wsoaw[96:144)
    constexpr int C4 = C3 + 9216;         // vp
    constexpr int C5 = C4 + 9216;         // op
    constexpr int C6 = C5 + 9216;         // ff
    constexpr int C7 = C6 + 18432;        // ffn1 (64,2,32)
    constexpr int C8 = C7 + 9216;         // ffn2
    if (i < C0)      pack_one<100, 96>(qk, wq, 0, 96, i);
    else if (i < C1) pack_one<96, 96>(ev, wv, 0, 96, i - C0);
    else if (i < C2) pack_one<96, 144>(so, wsoaw, 0, 96, i - C1);
    else if (i < C3) pack_one<96, 144>(aw, wsoaw, 96, 48, i - C2);
    else if (i < C4) pack_one<32, 32>(vp, wvp2, 0, 32, i - C3);
    else if (i < C5) pack_one<32, 32>(op, wop2, 0, 32, i - C4);
    else if (i < C6) pack_one<32, 32>(ffw, wff2, 0, 32, i - C5);
    else if (i < C7) pack_one<64, 32>(f1, wffn1, 0, 32, i - C6);
    else if (i < C8) pack_one<32, 32>(f2, wffn2, 0, 32, i - C7);
}

// ---------------------------------------------------------------------------
// copy_cl: pure coalesced copies (no gathers). 4 threads/pixel, half8 stores.
// ---------------------------------------------------------------------------
__global__ __launch_bounds__(256) void copy_cl_kernel(
    const float* __restrict__ frame, const float* __restrict__ srcframe,
    const float* __restrict__ ff, const float* __restrict__ fb,
    half_t* __restrict__ qin, half_t* __restrict__ fcl,
    half_t* __restrict__ o3rec, int H, int W)
{
    const int HW = H * W;
    const int p = threadIdx.x >> 2, sub = threadIdx.x & 3;
    const int q = blockIdx.x * 64 + p;
    const int b = blockIdx.y;
    const long fbase = (long)b * 96 * HW;
    const long rq = ((long)b * HW + q) * 112;
    const long rf = ((long)b * HW + q) * 96;
    const long r3 = ((long)b * HW + q) * 64;

    half8 c0, c2;
    #pragma unroll
    for (int d = 0; d < 8; ++d) {
        c0[d] = (half_t)frame[fbase + (long)(sub * 8 + d) * HW + q];
        c2[d] = (half_t)frame[fbase + (long)(64 + sub * 8 + d) * HW + q];
    }
    *(half8*)&fcl[rf + sub * 8] = c0;
    *(half8*)&fcl[rf + 64 + sub * 8] = c2;

    half8 fv, sv;
    #pragma unroll
    for (int d = 0; d < 8; ++d) {
        long off = fbase + (long)(32 + sub * 8 + d) * HW + q;
        fv[d] = (half_t)frame[off];
        sv[d] = (half_t)srcframe[off];
    }
    *(half8*)&qin[rq + 32 + sub * 8] = fv;
    *(half8*)&fcl[rf + 32 + sub * 8] = fv;
    *(half8*)&o3rec[r3 + 32 + sub * 8] = sv;

    if (sub == 0) {
        half8 fl = {};
        fl[0] = (half_t)ff[((long)(b * 2 + 1) * 2 + 0) * HW + q];
        fl[1] = (half_t)ff[((long)(b * 2 + 1) * 2 + 1) * HW + q];
        fl[2] = (half_t)fb[((long)(b * 2 + 0) * 2 + 0) * HW + q];
        fl[3] = (half_t)fb[((long)(b * 2 + 0) * 2 + 1) * HW + q];
        *(half8*)&qin[rq + 96] = fl;
    } else if (sub == 1) {
        half8 z = {};
        *(half8*)&qin[rq + 104] = z;
    }
}

// ---------------------------------------------------------------------------
// warp_cl: bilinear warps reading CL fcl records (16B half8 per corner-chunk).
// ---------------------------------------------------------------------------
__global__ __launch_bounds__(256) void warp_cl_kernel(
    const half_t* __restrict__ fcl, const float* __restrict__ ff,
    const float* __restrict__ fb, half_t* __restrict__ qin, int H, int W)
{
    const int HW = H * W;
    const int p = threadIdx.x >> 2, sub = threadIdx.x & 3;
    const int q = blockIdx.x * 64 + p;
    const int b = blockIdx.y;
    const int x = q % W, y = q / W;
    const long rq = ((long)b * HW + q) * 112;
    const half_t* fc = fcl + (long)b * HW * 96;

    const float fb0x = fb[((long)(b * 2 + 0) * 2 + 0) * HW + q];
    const float fb0y = fb[((long)(b * 2 + 0) * 2 + 1) * HW + q];
    const float ff1x = ff[((long)(b * 2 + 1) * 2 + 0) * HW + q];
    const float ff1y = ff[((long)(b * 2 + 1) * 2 + 1) * HW + q];

    #pragma unroll
    for (int t = 0; t < 2; ++t) {
        const float fx = t ? ff1x : fb0x;
        const float fy = t ? ff1y : fb0y;
        const int coff = t ? 64 : 0;
        float gx = (float)x + fx, gy = (float)y + fy;
        float x0f = floorf(gx), y0f = floorf(gy);
        float wx = gx - x0f, wy = gy - y0f;
        int x0 = min(max((int)x0f, 0), W - 1);
        int x1 = min(max((int)x0f + 1, 0), W - 1);
        int y0 = min(max((int)y0f, 0), H - 1);
        int y1 = min(max((int)y0f + 1, 0), H - 1);
        float w00 = (1.f - wx) * (1.f - wy), w10 = wx * (1.f - wy);
        float w01 = (1.f - wx) * wy, w11 = wx * wy;

        half8 v00 = *(const half8*)&fc[(long)(y0 * W + x0) * 96 + coff + sub * 8];
        half8 v10 = *(const half8*)&fc[(long)(y0 * W + x1) * 96 + coff + sub * 8];
        half8 v01 = *(const half8*)&fc[(long)(y1 * W + x0) * 96 + coff + sub * 8];
        half8 v11 = *(const half8*)&fc[(long)(y1 * W + x1) * 96 + coff + sub * 8];

        half8 st;
        #pragma unroll
        for (int d = 0; d < 8; ++d) {
            float v = (float)v00[d] * w00 + (float)v10[d] * w10 +
                      (float)v01[d] * w01 + (float)v11[d] * w11;
            st[d] = (half_t)v;
        }
        *(half8*)&qin[rq + coff + sub * 8] = st;
    }
}

// ---------------------------------------------------------------------------
// Channel-last implicit-GEMM 3x3 conv on MFMA f16 — v9: R18 structure
// (per-cb weight staging, CON co-split, 2 blocks/CU at ~70KB LDS) + act
// DOUBLE BUFFER: WRITEA targets the idle buffer BEFORE barrier1, so the
// all-waves-stalled region holds only WRITEW (28.8KB) instead of both.
// ---------------------------------------------------------------------------
template <int CREC, int CIN, int COUT, int DIL, bool LRELU, int RESID_MODE,
          int OUTC, int SPLIT, bool OUT_TGROUP, int RESREC, int CON>
__global__ __launch_bounds__(512, 2) void conv3x3_cl(
    const half_t* __restrict__ in, long in_stride,
    const half_t* __restrict__ w16,
    const float* __restrict__ bias0, const float* __restrict__ bias1,
    const void* __restrict__ resid, long resid_stride,
    half_t* __restrict__ out, long out_stride, int H, int W)
{
    constexpr int NCB = (CIN + 31) / 32;
    constexpr int S = 16 + 2 * DIL;
    constexpr int NF = CON / 16;                   // co-frags per block
    constexpr int COPAD = CON + 2;                 // +2 chunks -> 8-bank stagger
    constexpr int NLD = S * S * 4;                 // act half8 chunks / cb
    constexpr int NITEM = (NLD + 511) / 512;
    constexpr int WCH = 9 * 4 * COPAD;             // weight chunks / cb
    constexpr int NWIT = (WCH + 511) / 512;
    __shared__ half_t sa[2][NLD * 8];              // act double buffer
    __shared__ half_t sw[WCH * 8];

    const int n = blockIdx.y;
    const int cobase = blockIdx.z * CON;
    const int tile = blockIdx.x;
    const int tx = tile & 15, ty = tile >> 4;      // W==256 -> 16 tiles/row
    const int tid = threadIdx.x;
    const int wv = tid >> 6, lane = tid & 63;
    const int cl = lane & 15, jk = lane >> 4;

    floatx4 acc[2][NF] = {};

    const int gy0 = ty * 16 - DIL, gx0 = tx * 16 - DIL;
    const int HWl = H * W;
    const half_t* ib = in + (long)n * in_stride;

    // act staging geometry (loop-invariant)
    int pxv[NITEM], gofs[NITEM];
    bool inb[NITEM];
    #pragma unroll
    for (int k = 0; k < NITEM; ++k) {
        int i = tid + k * 512;
        int pix = i >> 2;
        int sy = pix / S, sx = pix - sy * S;
        int gy = gy0 + sy, gx = gx0 + sx;
        pxv[k] = pix;
        inb[k] = (i < NLD) && gy >= 0 && gy < H && gx >= 0 && gx < W;
        gofs[k] = gy * W + gx;
    }

    half8 ra[NITEM], rw[NWIT];
    auto LOADA = [&](int cb) {
        #pragma unroll
        for (int k = 0; k < NITEM; ++k) {
            int i = tid + k * 512;
            int c_g = cb * 4 + (i & 3);
            half8 v = {};
            if (inb[k] && (c_g * 8 + 8 <= CREC))
                v = *(const half8*)&ib[(long)gofs[k] * CREC + c_g * 8];
            ra[k] = v;
        }
    };
    auto WRITEA = [&](int buf) {
        #pragma unroll
        for (int k = 0; k < NITEM; ++k) {
            int i = tid + k * 512;
            if (i < NLD) {
                int pix = pxv[k], chunk = i & 3;
                *(half8*)&sa[buf][((pix << 2) + (chunk ^ ((pix >> 1) & 3))) << 3] = ra[k];
            }
        }
    };
    auto LOADW = [&](int cb) {
        #pragma unroll
        for (int k = 0; k < NWIT; ++k) {
            int j = tid + k * 512;
            int tj = j / COPAD;                    // tap*4 + jk
            int co = j - tj * COPAD;
            half8 v = {};
            if (j < WCH && co < CON) {
                int tap = tj >> 2, jj = tj & 3;
                v = *(const half8*)&w16[(((long)tap * NCB + cb) * COUT + cobase + co) * 32 + jj * 8];
            }
            rw[k] = v;
        }
    };
    auto WRITEW = [&]() {
        #pragma unroll
        for (int k = 0; k < NWIT; ++k) {
            int j = tid + k * 512;
            if (j < WCH) *(half8*)&sw[j * 8] = rw[k];
        }
    };

    LOADA(0); LOADW(0);
    WRITEA(0); WRITEW();
    __syncthreads();

    for (int cb = 0; cb < NCB; ++cb) {
        const int cur = cb & 1;
        if (cb + 1 < NCB) { LOADA(cb + 1); LOADW(cb + 1); }   // hidden by MFMA

        #pragma unroll
        for (int tap = 0; tap < 9; ++tap) {
            const int ky = tap / 3, kx = tap % 3;
            half8 af[2];
            #pragma unroll
            for (int m = 0; m < 2; ++m) {
                int pix = (wv * 2 + m + ky * DIL) * S + kx * DIL + cl;
                af[m] = *(const half8*)&sa[cur][((pix << 2) + (jk ^ ((pix >> 1) & 3))) << 3];
            }
            const int wbase = ((tap << 2) | jk) * COPAD + cl;
            #pragma unroll
            for (int nn = 0; nn < NF; ++nn) {
                half8 bf = *(const half8*)&sw[(wbase + nn * 16) * 8];
                acc[0][nn] = __builtin_amdgcn_mfma_f32_16x16x32_f16(af[0], bf, acc[0][nn], 0, 0, 0);
                acc[1][nn] = __builtin_amdgcn_mfma_f32_16x16x32_f16(af[1], bf, acc[1][nn], 0, 0, 0);
            }
        }

        if (cb + 1 < NCB) {
            WRITEA(cur ^ 1);               // idle buffer: pre-barrier, overlaps
            __syncthreads();               // all waves done reading sw
            WRITEW();
            __syncthreads();               // sw + sa[cur^1] visible
        }
    }

    // ---- epilogue. C map: co = cobase + nn*16 + cl; px = jk*4 + i ----
    const int x0 = tx * 16 + jk * 4;
    #pragma unroll
    for (int m = 0; m < 2; ++m) {
        const int yy = ty * 16 + wv * 2 + m;
        #pragma unroll
        for (int nn = 0; nn < NF; ++nn) {
            const int co = cobase + nn * 16 + cl;
            float bv = (co < SPLIT) ? bias0[co] : bias1[co - SPLIT];
            float r[4];
            #pragma unroll
            for (int i = 0; i < 4; ++i) r[i] = acc[m][nn][i] + bv;
            if constexpr (RESID_MODE == 1) {
                const float* rp = (const float*)resid + (long)n * resid_stride +
                                  (long)co * HWl + (long)yy * W + x0;
                float4 rv = *(const float4*)rp;
                r[0] += rv.x; r[1] += rv.y; r[2] += rv.z; r[3] += rv.w;
            } else if constexpr (RESID_MODE == 3) {
                const half_t* rp = (const half_t*)resid +
                                   ((long)n * HWl + (long)yy * W + x0) * RESREC + co;
                #pragma unroll
                for (int i = 0; i < 4; ++i) r[i] += (float)rp[i * RESREC];
            }
            if (LRELU) {
                #pragma unroll
                for (int i = 0; i < 4; ++i) r[i] = lrelu_f(r[i]);
            }
            if constexpr (OUT_TGROUP) {
                long base = ((long)(n * 3 + (co >> 5)) * HWl + (long)yy * W + x0) * 32 + (co & 31);
                #pragma unroll
                for (int i = 0; i < 4; ++i) out[base + i * 32] = (half_t)r[i];
            } else {
                long base = (long)n * out_stride + ((long)yy * W + x0) * OUTC + co;
                #pragma unroll
                for (int i = 0; i < 4; ++i) out[base + i * OUTC] = (half_t)r[i];
            }
        }
    }
}

// ---------------------------------------------------------------------------
// Fused deformable attention v3 (unchanged): one head per thread.
// ---------------------------------------------------------------------------
__global__ __launch_bounds__(256) void deform_v3(
    const half_t* __restrict__ v_cl, const half_t* __restrict__ offaw,
    const float* __restrict__ ff, const float* __restrict__ fb,
    half_t* __restrict__ out1, int H, int W)
{
    const int HW = H * W;
    const int bid = blockIdx.x;                   // 1024 tiles (8x8 px)
    const int swz = (bid & 7) * 128 + (bid >> 3); // bijective XCD swizzle
    const int tx = swz & 31, ty = swz >> 5;       // 32x32 tile grid
    const int b = blockIdx.y;
    const int p = threadIdx.x >> 2;               // pixel in tile (0..63)
    const int m = threadIdx.x & 3;                // head
    const int x = tx * 8 + (p & 7), y = ty * 8 + (p >> 3);
    const int q = y * W + x;

    const half_t* rec = &offaw[((long)b * HW + q) * 144];
    half8 offv[3];
    #pragma unroll
    for (int i = 0; i < 3; ++i) offv[i] = *(const half8*)&rec[m * 24 + i * 8];
    half4 awv[3];
    #pragma unroll
    for (int i = 0; i < 3; ++i) awv[i] = *(const half4*)&rec[96 + m * 12 + i * 4];

    float fbx = fb[((long)(b * 2 + 0) * 2 + 0) * HW + q];
    float fby = fb[((long)(b * 2 + 0) * 2 + 1) * HW + q];
    float ffx = ff[((long)(b * 2 + 1) * 2 + 0) * HW + q];
    float ffy = ff[((long)(b * 2 + 1) * 2 + 1) * HW + q];

    float a[12], mx = -1e30f;
    #pragma unroll
    for (int i = 0; i < 12; ++i) {
        a[i] = (float)awv[i >> 2][i & 3];
        mx = fmaxf(mx, a[i]);
    }
    float s = 0.f;
    #pragma unroll
    for (int i = 0; i < 12; ++i) { a[i] = expf(a[i] - mx); s += a[i]; }
    float inv = 1.f / s;

    float o[8] = {0, 0, 0, 0, 0, 0, 0, 0};
    #pragma unroll
    for (int l = 0; l < 3; ++l) {
        float fx = (l == 0) ? fbx : (l == 2) ? ffx : 0.f;
        float fy = (l == 0) ? fby : (l == 2) ? ffy : 0.f;
        const half_t* img = v_cl + (long)(b * 3 + l) * HW * 32 + m * 8;
        #pragma unroll
        for (int pp = 0; pp < 4; ++pp) {
            int oc = (l * 4 + pp) * 2;
            float gx = (float)x + (float)offv[oc >> 3][oc & 7] + fx;
            float gy = (float)y + (float)offv[(oc + 1) >> 3][(oc + 1) & 7] + fy;
            float wgt = a[l * 4 + pp] * inv;
            float x0f = floorf(gx), y0f = floorf(gy);
            float wx = gx - x0f, wy = gy - y0f;
            int x0 = (int)x0f, y0 = (int)y0f;
            #pragma unroll
            for (int t_ = 0; t_ < 4; ++t_) {
                int xi = x0 + (t_ & 1), yi = y0 + (t_ >> 1);
                float wt = ((t_ & 1) ? wx : 1.f - wx) *
                           ((t_ >> 1) ? wy : 1.f - wy) * wgt;
                if (xi >= 0 && xi < W && yi >= 0 && yi < H) {
                    const half8 vv = *(const half8*)&img[(long)(yi * W + xi) * 32];
                    #pragma unroll
                    for (int d = 0; d < 8; ++d) o[d] = fmaf(wt, (float)vv[d], o[d]);
                }
            }
        }
    }
    half8 st;
    #pragma unroll
    for (int d = 0; d < 8; ++d) st[d] = (half_t)o[d];
    *(half8*)&out1[((long)b * HW + q) * 32 + m * 8] = st;
}

// ---------------------------------------------------------------------------
// 1x1 conv (32->32) + lrelu, CL f16 in, fp32 planar out (final)
// ---------------------------------------------------------------------------
__global__ __launch_bounds__(256) void conv1x1_f16(
    const half_t* __restrict__ in, const float* __restrict__ w,
    const float* __restrict__ bias, float* __restrict__ out, int HW)
{
    int q = blockIdx.x * 256 + threadIdx.x;
    if (q >= HW) return;
    long b = blockIdx.y;
    const half8* ip = (const half8*)&in[((long)b * HW + q) * 32];
    half8 vv[4];
    #pragma unroll
    for (int i = 0; i < 4; ++i) vv[i] = ip[i];
    float v[32];
    #pragma unroll
    for (int ci = 0; ci < 32; ++ci) v[ci] = (float)vv[ci >> 3][ci & 7];
    float* ob = out + b * 32 * HW;
    #pragma unroll
    for (int co = 0; co < 32; ++co) {
        float acc = bias[co];
        #pragma unroll
        for (int ci = 0; ci < 32; ++ci) acc = fmaf(w[co * 32 + ci], v[ci], acc);
        ob[(long)co * HW + q] = lrelu_f(acc);
    }
}

// ---------------------------------------------------------------------------
extern "C" void kernel_launch(void* const* d_in, const int* in_sizes, int n_in,
                              void* d_out, int out_size, void* d_ws, size_t ws_size,
                              hipStream_t stream)
{
    (void)in_sizes; (void)n_in; (void)out_size; (void)ws_size;
    const int H = 256, W = 256, HW = H * W, B = 2;

    const float* frame    = (const float*)d_in[0];
    const float* srcframe = (const float*)d_in[1];
    const float* ff       = (const float*)d_in[2];
    const float* fb       = (const float*)d_in[3];
    const float* emb_qk_w = (const float*)d_in[4];
    const float* emb_qk_b = (const float*)d_in[5];
    const float* emb_v_w  = (const float*)d_in[6];
    const float* emb_v_b  = (const float*)d_in[7];
    const float* so_w     = (const float*)d_in[8];
    const float* so_b     = (const float*)d_in[9];
    const float* aw_w     = (const float*)d_in[10];
    const float* aw_b     = (const float*)d_in[11];
    const float* vp_w     = (const float*)d_in[12];
    const float* vp_b     = (const float*)d_in[13];
    const float* op_w     = (const float*)d_in[14];
    const float* op_b     = (const float*)d_in[15];
    const float* ff_w     = (const float*)d_in[16];
    const float* ff_b     = (const float*)d_in[17];
    const float* ffn1_w   = (const float*)d_in[18];
    const float* ffn1_b   = (const float*)d_in[19];
    const float* ffn2_w   = (const float*)d_in[20];
    const float* ffn2_b   = (const float*)d_in[21];
    const float* fus_w    = (const float*)d_in[22];
    const float* fus_b    = (const float*)d_in[23];

    half_t* hw = (half_t*)d_ws;
    half_t* q_in_cl = hw;                   // 2*HW*112
    half_t* fcl     = hw + 14680064L;       // 2*HW*96
    half_t* value_g = hw + 27262976L;       // 6*HW*32
    half_t* offaw   = hw + 14680064L;       // 2*HW*144 (alias fcl+value_g)
    half_t* query_c = hw + 39845888L;       // 2*HW*96
    half_t* v_cl    = hw + 52428800L;       // 6*HW*32
    half_t* out1    = hw + 65011712L;       // 2*HW*32
    half_t* out2    = hw + 69206016L;
    half_t* o3rec   = hw + 73400320L;       // 2*HW*64 (out3 | src1)
    half_t* ffnb    = hw + 81788928L;
    half_t* out4    = hw + 85983232L;
    half_t* wq      = hw + 90177536L;
    half_t* wv      = hw + 90288128L;
    half_t* wsoaw   = hw + 90371072L;
    half_t* wvp     = hw + 90495488L;
    half_t* wop     = hw + 90504704L;
    half_t* wff     = hw + 90513920L;
    half_t* wffn1   = hw + 90523136L;
    half_t* wffn2   = hw + 90541568L;

    dim3 blk(256);
    dim3 cblk(512);

    prep_w_all<<<(373248 + 255) / 256, blk, 0, stream>>>(
        emb_qk_w, emb_v_w, so_w, aw_w, vp_w, op_w, ff_w, ffn1_w, ffn2_w,
        wq, wv, wsoaw, wvp, wop, wff, wffn1, wffn2);

    copy_cl_kernel<<<dim3(HW / 64, B), blk, 0, stream>>>(frame, srcframe, ff, fb,
                                                         q_in_cl, fcl, o3rec, H, W);
    warp_cl_kernel<<<dim3(HW / 64, B), blk, 0, stream>>>(fcl, ff, fb, q_in_cl, H, W);

    // query = lrelu(conv(q_in, emb_qk))            CL 112 -> CL 96  (2x48 co)
    conv3x3_cl<112, 100, 96, 1, true, 0, 96, 96, false, 0, 48>
        <<<dim3(256, B, 2), cblk, 0, stream>>>(q_in_cl, (long)HW * 112, wq, emb_qk_b,
                                               nullptr, nullptr, 0, query_c,
                                               (long)HW * 96, H, W);
    // value = lrelu(conv(frame_cl, emb_v))         CL 96 -> [6][pix][32] (2x48)
    conv3x3_cl<96, 96, 96, 1, true, 0, 32, 96, true, 0, 48>
        <<<dim3(256, B, 2), cblk, 0, stream>>>(fcl, (long)HW * 96, wv, emb_v_b,
                                               nullptr, nullptr, 0, value_g, 0, H, W);
    // v = conv(value, vp) per image               CL 32 -> CL 32
    conv3x3_cl<32, 32, 32, 1, false, 0, 32, 32, false, 0, 32>
        <<<dim3(256, 6, 1), cblk, 0, stream>>>(value_g, (long)HW * 32, wvp, vp_b,
                                               nullptr, nullptr, 0, v_cl,
                                               (long)HW * 32, H, W);
    // off|aw = conv(query, so|aw)                  CL 96 -> CL 144 (3x48 co)
    conv3x3_cl<96, 96, 144, 1, false, 0, 144, 96, false, 0, 48>
        <<<dim3(256, B, 3), cblk, 0, stream>>>(query_c, (long)HW * 96, wsoaw, so_b,
                                               aw_b, nullptr, 0, offaw,
                                               (long)HW * 144, H, W);
    // out1 = deformable attention (one head per thread, 8x8 tiles)
    deform_v3<<<dim3(1024, B), blk, 0, stream>>>(v_cl, offaw, ff, fb, out1, H, W);
    // out2 = conv(out1, op)
    conv3x3_cl<32, 32, 32, 1, false, 0, 32, 32, false, 0, 32>
        <<<dim3(256, B, 1), cblk, 0, stream>>>(out1, (long)HW * 32, wop, op_b,
                                               nullptr, nullptr, 0, out2,
                                               (long)HW * 32, H, W);
    // out3 = conv(out2, ff_w) + frame[:,1]  -> o3rec lower half (record 64)
    conv3x3_cl<32, 32, 32, 1, false, 1, 64, 32, false, 0, 32>
        <<<dim3(256, B, 1), cblk, 0, stream>>>(out2, (long)HW * 32, wff, ff_b,
                                               nullptr, frame + 32L * HW, 96L * HW,
                                               o3rec, (long)HW * 64, H, W);
    // ffn = lrelu(conv_dil2(o3rec[out3|src1], ffn1))
    conv3x3_cl<64, 64, 32, 2, true, 0, 32, 32, false, 0, 32>
        <<<dim3(256, B, 1), cblk, 0, stream>>>(o3rec, (long)HW * 64, wffn1, ffn1_b,
                                               nullptr, nullptr, 0, ffnb,
                                               (long)HW * 32, H, W);
    // out4 = out3 + conv(ffn, ffn2)   (resid = o3rec CL stride 64)
    conv3x3_cl<32, 32, 32, 1, false, 3, 32, 32, false, 64, 32>
        <<<dim3(256, B, 1), cblk, 0, stream>>>(ffnb, (long)HW * 32, wffn2, ffn2_b,
                                               nullptr, o3rec, 0, out4,
                                               (long)HW * 32, H, W);
    // d_out = lrelu(conv1x1(out4, fus))
    conv1x1_f16<<<dim3(HW / 256, B), blk, 0, stream>>>(out4, fus_w, fus_b,
                                                       (float*)d_out, HW);
}

// Round 24
// 268.411 us; speedup vs baseline: 1.1911x; 1.0336x over previous
//
#include <hip/hip_runtime.h>
#include <cmath>

typedef _Float16 half_t;
typedef _Float16 half8 __attribute__((ext_vector_type(8)));
typedef _Float16 half4 __attribute__((ext_vector_type(4)));
typedef float floatx4 __attribute__((ext_vector_type(4)));

__device__ __forceinline__ float lrelu_f(float v) { return v >= 0.f ? v : 0.1f * v; }

// ---------------------------------------------------------------------------
// Weight pack helper: OIHW fp32 -> f16 [tap][cinblk][co_total][ci(32)]
// ---------------------------------------------------------------------------
template <int CIN, int COTOT>
__device__ __forceinline__ void pack_one(const float* __restrict__ w,
                                         half_t* __restrict__ o,
                                         int co_off, int co_n, int i)
{
    constexpr int NCB = (CIN + 31) / 32;
    int ci = i & 31;
    int t = i >> 5;
    int col = t % co_n; t /= co_n;
    int cb = t % NCB;
    int tap = t / NCB;
    int cg = cb * 32 + ci;
    float v = (cg < CIN) ? w[((long)col * CIN + cg) * 9 + tap] : 0.f;
    o[(((long)tap * NCB + cb) * COTOT + co_off + col) * 32 + ci] = (half_t)v;
}

// All 9 weight tensors packed in ONE launch (segment by linear index).
__global__ __launch_bounds__(256) void prep_w_all(
    const float* __restrict__ qk, const float* __restrict__ ev,
    const float* __restrict__ so, const float* __restrict__ aw,
    const float* __restrict__ vp, const float* __restrict__ op,
    const float* __restrict__ ffw, const float* __restrict__ f1,
    const float* __restrict__ f2,
    half_t* wq, half_t* wv, half_t* wsoaw, half_t* wvp2, half_t* wop2,
    half_t* wff2, half_t* wffn1, half_t* wffn2)
{
    int i = blockIdx.x * 256 + threadIdx.x;
    constexpr int C0 = 110592;            // qk  (CIN100,NCB4,96)
    constexpr int C1 = C0 + 82944;        // ev  (96,3,96)
    constexpr int C2 = C1 + 82944;        // so  -> wsoaw[0:96)
    constexpr int C3 = C2 + 41472;        // aw  -> wsoaw[96:144)
    constexpr int C4 = C3 + 9216;         // vp
    constexpr int C5 = C4 + 9216;         // op
    constexpr int C6 = C5 + 9216;         // ff
    constexpr int C7 = C6 + 18432;        // ffn1 (64,2,32)
    constexpr int C8 = C7 + 9216;         // ffn2
    if (i < C0)      pack_one<100, 96>(qk, wq, 0, 96, i);
    else if (i < C1) pack_one<96, 96>(ev, wv, 0, 96, i - C0);
    else if (i < C2) pack_one<96, 144>(so, wsoaw, 0, 96, i - C1);
    else if (i < C3) pack_one<96, 144>(aw, wsoaw, 96, 48, i - C2);
    else if (i < C4) pack_one<32, 32>(vp, wvp2, 0, 32, i - C3);
    else if (i < C5) pack_one<32, 32>(op, wop2, 0, 32, i - C4);
    else if (i < C6) pack_one<32, 32>(ffw, wff2, 0, 32, i - C5);
    else if (i < C7) pack_one<64, 32>(f1, wffn1, 0, 32, i - C6);
    else if (i < C8) pack_one<32, 32>(f2, wffn2, 0, 32, i - C7);
}

// ---------------------------------------------------------------------------
// copy_cl: pure coalesced copies (no gathers). 4 threads/pixel, half8 stores.
// ---------------------------------------------------------------------------
__global__ __launch_bounds__(256) void copy_cl_kernel(
    const float* __restrict__ frame, const float* __restrict__ srcframe,
    const float* __restrict__ ff, const float* __restrict__ fb,
    half_t* __restrict__ qin, half_t* __restrict__ fcl,
    half_t* __restrict__ o3rec, int H, int W)
{
    const int HW = H * W;
    const int p = threadIdx.x >> 2, sub = threadIdx.x & 3;
    const int q = blockIdx.x * 64 + p;
    const int b = blockIdx.y;
    const long fbase = (long)b * 96 * HW;
    const long rq = ((long)b * HW + q) * 112;
    const long rf = ((long)b * HW + q) * 96;
    const long r3 = ((long)b * HW + q) * 64;

    half8 c0, c2;
    #pragma unroll
    for (int d = 0; d < 8; ++d) {
        c0[d] = (half_t)frame[fbase + (long)(sub * 8 + d) * HW + q];
        c2[d] = (half_t)frame[fbase + (long)(64 + sub * 8 + d) * HW + q];
    }
    *(half8*)&fcl[rf + sub * 8] = c0;
    *(half8*)&fcl[rf + 64 + sub * 8] = c2;

    half8 fv, sv;
    #pragma unroll
    for (int d = 0; d < 8; ++d) {
        long off = fbase + (long)(32 + sub * 8 + d) * HW + q;
        fv[d] = (half_t)frame[off];
        sv[d] = (half_t)srcframe[off];
    }
    *(half8*)&qin[rq + 32 + sub * 8] = fv;
    *(half8*)&fcl[rf + 32 + sub * 8] = fv;
    *(half8*)&o3rec[r3 + 32 + sub * 8] = sv;

    if (sub == 0) {
        half8 fl = {};
        fl[0] = (half_t)ff[((long)(b * 2 + 1) * 2 + 0) * HW + q];
        fl[1] = (half_t)ff[((long)(b * 2 + 1) * 2 + 1) * HW + q];
        fl[2] = (half_t)fb[((long)(b * 2 + 0) * 2 + 0) * HW + q];
        fl[3] = (half_t)fb[((long)(b * 2 + 0) * 2 + 1) * HW + q];
        *(half8*)&qin[rq + 96] = fl;
    } else if (sub == 1) {
        half8 z = {};
        *(half8*)&qin[rq + 104] = z;
    }
}

// ---------------------------------------------------------------------------
// warp_cl: bilinear warps reading CL fcl records (16B half8 per corner-chunk).
// ---------------------------------------------------------------------------
__global__ __launch_bounds__(256) void warp_cl_kernel(
    const half_t* __restrict__ fcl, const float* __restrict__ ff,
    const float* __restrict__ fb, half_t* __restrict__ qin, int H, int W)
{
    const int HW = H * W;
    const int p = threadIdx.x >> 2, sub = threadIdx.x & 3;
    const int q = blockIdx.x * 64 + p;
    const int b = blockIdx.y;
    const int x = q % W, y = q / W;
    const long rq = ((long)b * HW + q) * 112;
    const half_t* fc = fcl + (long)b * HW * 96;

    const float fb0x = fb[((long)(b * 2 + 0) * 2 + 0) * HW + q];
    const float fb0y = fb[((long)(b * 2 + 0) * 2 + 1) * HW + q];
    const float ff1x = ff[((long)(b * 2 + 1) * 2 + 0) * HW + q];
    const float ff1y = ff[((long)(b * 2 + 1) * 2 + 1) * HW + q];

    #pragma unroll
    for (int t = 0; t < 2; ++t) {
        const float fx = t ? ff1x : fb0x;
        const float fy = t ? ff1y : fb0y;
        const int coff = t ? 64 : 0;
        float gx = (float)x + fx, gy = (float)y + fy;
        float x0f = floorf(gx), y0f = floorf(gy);
        float wx = gx - x0f, wy = gy - y0f;
        int x0 = min(max((int)x0f, 0), W - 1);
        int x1 = min(max((int)x0f + 1, 0), W - 1);
        int y0 = min(max((int)y0f, 0), H - 1);
        int y1 = min(max((int)y0f + 1, 0), H - 1);
        float w00 = (1.f - wx) * (1.f - wy), w10 = wx * (1.f - wy);
        float w01 = (1.f - wx) * wy, w11 = wx * wy;

        half8 v00 = *(const half8*)&fc[(long)(y0 * W + x0) * 96 + coff + sub * 8];
        half8 v10 = *(const half8*)&fc[(long)(y0 * W + x1) * 96 + coff + sub * 8];
        half8 v01 = *(const half8*)&fc[(long)(y1 * W + x0) * 96 + coff + sub * 8];
        half8 v11 = *(const half8*)&fc[(long)(y1 * W + x1) * 96 + coff + sub * 8];

        half8 st;
        #pragma unroll
        for (int d = 0; d < 8; ++d) {
            float v = (float)v00[d] * w00 + (float)v10[d] * w10 +
                      (float)v01[d] * w01 + (float)v11[d] * w11;
            st[d] = (half_t)v;
        }
        *(half8*)&qin[rq + coff + sub * 8] = st;
    }
}

// ---------------------------------------------------------------------------
// Channel-last implicit-GEMM 3x3 conv on MFMA f16 — v7 (BEST MEASURED, R18):
// 16x16 tile, 8 waves x 2 rows, weights in LDS (per-cb staging), reg prefetch
// of next cb, COUT-SPLIT via blockIdx.z -> ~49.5KB LDS -> 2 blocks/CU.
// ---------------------------------------------------------------------------
template <int CREC, int CIN, int COUT, int DIL, bool LRELU, int RESID_MODE,
          int OUTC, int SPLIT, bool OUT_TGROUP, int RESREC, int CON>
__global__ __launch_bounds__(512, 2) void conv3x3_cl(
    const half_t* __restrict__ in, long in_stride,
    const half_t* __restrict__ w16,
    const float* __restrict__ bias0, const float* __restrict__ bias1,
    const void* __restrict__ resid, long resid_stride,
    half_t* __restrict__ out, long out_stride, int H, int W)
{
    constexpr int NCB = (CIN + 31) / 32;
    constexpr int S = 16 + 2 * DIL;
    constexpr int NF = CON / 16;                   // co-frags per block
    constexpr int COPAD = CON + 2;                 // +2 chunks -> 8-bank stagger
    constexpr int NLD = S * S * 4;                 // act half8 chunks / cb
    constexpr int NITEM = (NLD + 511) / 512;
    constexpr int WCH = 9 * 4 * COPAD;             // weight chunks / cb
    constexpr int NWIT = (WCH + 511) / 512;
    __shared__ half_t sa[NLD * 8];
    __shared__ half_t sw[WCH * 8];

    const int n = blockIdx.y;
    const int cobase = blockIdx.z * CON;
    const int tile = blockIdx.x;
    const int tx = tile & 15, ty = tile >> 4;      // W==256 -> 16 tiles/row
    const int tid = threadIdx.x;
    const int wv = tid >> 6, lane = tid & 63;
    const int cl = lane & 15, jk = lane >> 4;

    floatx4 acc[2][NF] = {};

    const int gy0 = ty * 16 - DIL, gx0 = tx * 16 - DIL;
    const int HWl = H * W;
    const half_t* ib = in + (long)n * in_stride;

    // act staging geometry (loop-invariant)
    int pxv[NITEM], gofs[NITEM];
    bool inb[NITEM];
    #pragma unroll
    for (int k = 0; k < NITEM; ++k) {
        int i = tid + k * 512;
        int pix = i >> 2;
        int sy = pix / S, sx = pix - sy * S;
        int gy = gy0 + sy, gx = gx0 + sx;
        pxv[k] = pix;
        inb[k] = (i < NLD) && gy >= 0 && gy < H && gx >= 0 && gx < W;
        gofs[k] = gy * W + gx;
    }

    half8 ra[NITEM], rw[NWIT];
    auto LOADA = [&](int cb) {
        #pragma unroll
        for (int k = 0; k < NITEM; ++k) {
            int i = tid + k * 512;
            int c_g = cb * 4 + (i & 3);
            half8 v = {};
            if (inb[k] && (c_g * 8 + 8 <= CREC))
                v = *(const half8*)&ib[(long)gofs[k] * CREC + c_g * 8];
            ra[k] = v;
        }
    };
    auto WRITEA = [&]() {
        #pragma unroll
        for (int k = 0; k < NITEM; ++k) {
            int i = tid + k * 512;
            if (i < NLD) {
                int pix = pxv[k], chunk = i & 3;
                *(half8*)&sa[((pix << 2) + (chunk ^ ((pix >> 1) & 3))) << 3] = ra[k];
            }
        }
    };
    auto LOADW = [&](int cb) {
        #pragma unroll
        for (int k = 0; k < NWIT; ++k) {
            int j = tid + k * 512;
            int tj = j / COPAD;                    // tap*4 + jk
            int co = j - tj * COPAD;
            half8 v = {};
            if (j < WCH && co < CON) {
                int tap = tj >> 2, jj = tj & 3;
                v = *(const half8*)&w16[(((long)tap * NCB + cb) * COUT + cobase + co) * 32 + jj * 8];
            }
            rw[k] = v;
        }
    };
    auto WRITEW = [&]() {
        #pragma unroll
        for (int k = 0; k < NWIT; ++k) {
            int j = tid + k * 512;
            if (j < WCH) *(half8*)&sw[j * 8] = rw[k];
        }
    };

    LOADA(0); LOADW(0);
    WRITEA(); WRITEW();
    __syncthreads();

    for (int cb = 0; cb < NCB; ++cb) {
        if (cb + 1 < NCB) { LOADA(cb + 1); LOADW(cb + 1); }   // hidden by MFMA

        #pragma unroll
        for (int tap = 0; tap < 9; ++tap) {
            const int ky = tap / 3, kx = tap % 3;
            half8 af[2];
            #pragma unroll
            for (int m = 0; m < 2; ++m) {
                int pix = (wv * 2 + m + ky * DIL) * S + kx * DIL + cl;
                af[m] = *(const half8*)&sa[((pix << 2) + (jk ^ ((pix >> 1) & 3))) << 3];
            }
            const int wbase = ((tap << 2) | jk) * COPAD + cl;
            #pragma unroll
            for (int nn = 0; nn < NF; ++nn) {
                half8 bf = *(const half8*)&sw[(wbase + nn * 16) * 8];
                acc[0][nn] = __builtin_amdgcn_mfma_f32_16x16x32_f16(af[0], bf, acc[0][nn], 0, 0, 0);
                acc[1][nn] = __builtin_amdgcn_mfma_f32_16x16x32_f16(af[1], bf, acc[1][nn], 0, 0, 0);
            }
        }

        if (cb + 1 < NCB) {
            __syncthreads();               // all waves done reading sa/sw
            WRITEA(); WRITEW();
            __syncthreads();               // new cb visible
        }
    }

    // ---- epilogue. C map: co = cobase + nn*16 + cl; px = jk*4 + i ----
    const int x0 = tx * 16 + jk * 4;
    #pragma unroll
    for (int m = 0; m < 2; ++m) {
        const int yy = ty * 16 + wv * 2 + m;
        #pragma unroll
        for (int nn = 0; nn < NF; ++nn) {
            const int co = cobase + nn * 16 + cl;
            float bv = (co < SPLIT) ? bias0[co] : bias1[co - SPLIT];
            float r[4];
            #pragma unroll
            for (int i = 0; i < 4; ++i) r[i] = acc[m][nn][i] + bv;
            if constexpr (RESID_MODE == 1) {
                const float* rp = (const float*)resid + (long)n * resid_stride +
                                  (long)co * HWl + (long)yy * W + x0;
                float4 rv = *(const float4*)rp;
                r[0] += rv.x; r[1] += rv.y; r[2] += rv.z; r[3] += rv.w;
            } else if constexpr (RESID_MODE == 3) {
                const half_t* rp = (const half_t*)resid +
                                   ((long)n * HWl + (long)yy * W + x0) * RESREC + co;
                #pragma unroll
                for (int i = 0; i < 4; ++i) r[i] += (float)rp[i * RESREC];
            }
            if (LRELU) {
                #pragma unroll
                for (int i = 0; i < 4; ++i) r[i] = lrelu_f(r[i]);
            }
            if constexpr (OUT_TGROUP) {
                long base = ((long)(n * 3 + (co >> 5)) * HWl + (long)yy * W + x0) * 32 + (co & 31);
                #pragma unroll
                for (int i = 0; i < 4; ++i) out[base + i * 32] = (half_t)r[i];
            } else {
                long base = (long)n * out_stride + ((long)yy * W + x0) * OUTC + co;
                #pragma unroll
                for (int i = 0; i < 4; ++i) out[base + i * OUTC] = (half_t)r[i];
            }
        }
    }
}

// ---------------------------------------------------------------------------
// Fused deformable attention v3: one head per thread.
// ---------------------------------------------------------------------------
__global__ __launch_bounds__(256) void deform_v3(
    const half_t* __restrict__ v_cl, const half_t* __restrict__ offaw,
    const float* __restrict__ ff, const float* __restrict__ fb,
    half_t* __restrict__ out1, int H, int W)
{
    const int HW = H * W;
    const int bid = blockIdx.x;                   // 1024 tiles (8x8 px)
    const int swz = (bid & 7) * 128 + (bid >> 3); // bijective XCD swizzle
    const int tx = swz & 31, ty = swz >> 5;       // 32x32 tile grid
    const int b = blockIdx.y;
    const int p = threadIdx.x >> 2;               // pixel in tile (0..63)
    const int m = threadIdx.x & 3;                // head
    const int x = tx * 8 + (p & 7), y = ty * 8 + (p >> 3);
    const int q = y * W + x;

    const half_t* rec = &offaw[((long)b * HW + q) * 144];
    half8 offv[3];
    #pragma unroll
    for (int i = 0; i < 3; ++i) offv[i] = *(const half8*)&rec[m * 24 + i * 8];
    half4 awv[3];
    #pragma unroll
    for (int i = 0; i < 3; ++i) awv[i] = *(const half4*)&rec[96 + m * 12 + i * 4];

    float fbx = fb[((long)(b * 2 + 0) * 2 + 0) * HW + q];
    float fby = fb[((long)(b * 2 + 0) * 2 + 1) * HW + q];
    float ffx = ff[((long)(b * 2 + 1) * 2 + 0) * HW + q];
    float ffy = ff[((long)(b * 2 + 1) * 2 + 1) * HW + q];

    float a[12], mx = -1e30f;
    #pragma unroll
    for (int i = 0; i < 12; ++i) {
        a[i] = (float)awv[i >> 2][i & 3];
        mx = fmaxf(mx, a[i]);
    }
    float s = 0.f;
    #pragma unroll
    for (int i = 0; i < 12; ++i) { a[i] = expf(a[i] - mx); s += a[i]; }
    float inv = 1.f / s;

    float o[8] = {0, 0, 0, 0, 0, 0, 0, 0};
    #pragma unroll
    for (int l = 0; l < 3; ++l) {
        float fx = (l == 0) ? fbx : (l == 2) ? ffx : 0.f;
        float fy = (l == 0) ? fby : (l == 2) ? ffy : 0.f;
        const half_t* img = v_cl + (long)(b * 3 + l) * HW * 32 + m * 8;
        #pragma unroll
        for (int pp = 0; pp < 4; ++pp) {
            int oc = (l * 4 + pp) * 2;
            float gx = (float)x + (float)offv[oc >> 3][oc & 7] + fx;
            float gy = (float)y + (float)offv[(oc + 1) >> 3][(oc + 1) & 7] + fy;
            float wgt = a[l * 4 + pp] * inv;
            float x0f = floorf(gx), y0f = floorf(gy);
            float wx = gx - x0f, wy = gy - y0f;
            int x0 = (int)x0f, y0 = (int)y0f;
            #pragma unroll
            for (int t_ = 0; t_ < 4; ++t_) {
                int xi = x0 + (t_ & 1), yi = y0 + (t_ >> 1);
                float wt = ((t_ & 1) ? wx : 1.f - wx) *
                           ((t_ >> 1) ? wy : 1.f - wy) * wgt;
                if (xi >= 0 && xi < W && yi >= 0 && yi < H) {
                    const half8 vv = *(const half8*)&img[(long)(yi * W + xi) * 32];
                    #pragma unroll
                    for (int d = 0; d < 8; ++d) o[d] = fmaf(wt, (float)vv[d], o[d]);
                }
            }
        }
    }
    half8 st;
    #pragma unroll
    for (int d = 0; d < 8; ++d) st[d] = (half_t)o[d];
    *(half8*)&out1[((long)b * HW + q) * 32 + m * 8] = st;
}

// ---------------------------------------------------------------------------
// 1x1 conv (32->32) + lrelu, CL f16 in, fp32 planar out (final)
// ---------------------------------------------------------------------------
__global__ __launch_bounds__(256) void conv1x1_f16(
    const half_t* __restrict__ in, const float* __restrict__ w,
    const float* __restrict__ bias, float* __restrict__ out, int HW)
{
    int q = blockIdx.x * 256 + threadIdx.x;
    if (q >= HW) return;
    long b = blockIdx.y;
    const half8* ip = (const half8*)&in[((long)b * HW + q) * 32];
    half8 vv[4];
    #pragma unroll
    for (int i = 0; i < 4; ++i) vv[i] = ip[i];
    float v[32];
    #pragma unroll
    for (int ci = 0; ci < 32; ++ci) v[ci] = (float)vv[ci >> 3][ci & 7];
    float* ob = out + b * 32 * HW;
    #pragma unroll
    for (int co = 0; co < 32; ++co) {
        float acc = bias[co];
        #pragma unroll
        for (int ci = 0; ci < 32; ++ci) acc = fmaf(w[co * 32 + ci], v[ci], acc);
        ob[(long)co * HW + q] = lrelu_f(acc);
    }
}

// ---------------------------------------------------------------------------
extern "C" void kernel_launch(void* const* d_in, const int* in_sizes, int n_in,
                              void* d_out, int out_size, void* d_ws, size_t ws_size,
                              hipStream_t stream)
{
    (void)in_sizes; (void)n_in; (void)out_size; (void)ws_size;
    const int H = 256, W = 256, HW = H * W, B = 2;

    const float* frame    = (const float*)d_in[0];
    const float* srcframe = (const float*)d_in[1];
    const float* ff       = (const float*)d_in[2];
    const float* fb       = (const float*)d_in[3];
    const float* emb_qk_w = (const float*)d_in[4];
    const float* emb_qk_b = (const float*)d_in[5];
    const float* emb_v_w  = (const float*)d_in[6];
    const float* emb_v_b  = (const float*)d_in[7];
    const float* so_w     = (const float*)d_in[8];
    const float* so_b     = (const float*)d_in[9];
    const float* aw_w     = (const float*)d_in[10];
    const float* aw_b     = (const float*)d_in[11];
    const float* vp_w     = (const float*)d_in[12];
    const float* vp_b     = (const float*)d_in[13];
    const float* op_w     = (const float*)d_in[14];
    const float* op_b     = (const float*)d_in[15];
    const float* ff_w     = (const float*)d_in[16];
    const float* ff_b     = (const float*)d_in[17];
    const float* ffn1_w   = (const float*)d_in[18];
    const float* ffn1_b   = (const float*)d_in[19];
    const float* ffn2_w   = (const float*)d_in[20];
    const float* ffn2_b   = (const float*)d_in[21];
    const float* fus_w    = (const float*)d_in[22];
    const float* fus_b    = (const float*)d_in[23];

    half_t* hw = (half_t*)d_ws;
    half_t* q_in_cl = hw;                   // 2*HW*112
    half_t* fcl     = hw + 14680064L;       // 2*HW*96
    half_t* value_g = hw + 27262976L;       // 6*HW*32
    half_t* offaw   = hw + 14680064L;       // 2*HW*144 (alias fcl+value_g)
    half_t* query_c = hw + 39845888L;       // 2*HW*96
    half_t* v_cl    = hw + 52428800L;       // 6*HW*32
    half_t* out1    = hw + 65011712L;       // 2*HW*32
    half_t* out2    = hw + 69206016L;
    half_t* o3rec   = hw + 73400320L;       // 2*HW*64 (out3 | src1)
    half_t* ffnb    = hw + 81788928L;
    half_t* out4    = hw + 85983232L;
    half_t* wq      = hw + 90177536L;
    half_t* wv      = hw + 90288128L;
    half_t* wsoaw   = hw + 90371072L;
    half_t* wvp     = hw + 90495488L;
    half_t* wop     = hw + 90504704L;
    half_t* wff     = hw + 90513920L;
    half_t* wffn1   = hw + 90523136L;
    half_t* wffn2   = hw + 90541568L;

    dim3 blk(256);
    dim3 cblk(512);

    prep_w_all<<<(373248 + 255) / 256, blk, 0, stream>>>(
        emb_qk_w, emb_v_w, so_w, aw_w, vp_w, op_w, ff_w, ffn1_w, ffn2_w,
        wq, wv, wsoaw, wvp, wop, wff, wffn1, wffn2);

    copy_cl_kernel<<<dim3(HW / 64, B), blk, 0, stream>>>(frame, srcframe, ff, fb,
                                                         q_in_cl, fcl, o3rec, H, W);
    warp_cl_kernel<<<dim3(HW / 64, B), blk, 0, stream>>>(fcl, ff, fb, q_in_cl, H, W);

    // query = lrelu(conv(q_in, emb_qk))            CL 112 -> CL 96  (2x48 co)
    conv3x3_cl<112, 100, 96, 1, true, 0, 96, 96, false, 0, 48>
        <<<dim3(256, B, 2), cblk, 0, stream>>>(q_in_cl, (long)HW * 112, wq, emb_qk_b,
                                               nullptr, nullptr, 0, query_c,
                                               (long)HW * 96, H, W);
    // value = lrelu(conv(frame_cl, emb_v))         CL 96 -> [6][pix][32] (2x48)
    conv3x3_cl<96, 96, 96, 1, true, 0, 32, 96, true, 0, 48>
        <<<dim3(256, B, 2), cblk, 0, stream>>>(fcl, (long)HW * 96, wv, emb_v_b,
                                               nullptr, nullptr, 0, value_g, 0, H, W);
    // v = conv(value, vp) per image               CL 32 -> CL 32
    conv3x3_cl<32, 32, 32, 1, false, 0, 32, 32, false, 0, 32>
        <<<dim3(256, 6, 1), cblk, 0, stream>>>(value_g, (long)HW * 32, wvp, vp_b,
                                               nullptr, nullptr, 0, v_cl,
                                               (long)HW * 32, H, W);
    // off|aw = conv(query, so|aw)                  CL 96 -> CL 144 (3x48 co)
    conv3x3_cl<96, 96, 144, 1, false, 0, 144, 96, false, 0, 48>
        <<<dim3(256, B, 3), cblk, 0, stream>>>(query_c, (long)HW * 96, wsoaw, so_b,
                                               aw_b, nullptr, 0, offaw,
                                               (long)HW * 144, H, W);
    // out1 = deformable attention (one head per thread, 8x8 tiles)
    deform_v3<<<dim3(1024, B), blk, 0, stream>>>(v_cl, offaw, ff, fb, out1, H, W);
    // out2 = conv(out1, op)
    conv3x3_cl<32, 32, 32, 1, false, 0, 32, 32, false, 0, 32>
        <<<dim3(256, B, 1), cblk, 0, stream>>>(out1, (long)HW * 32, wop, op_b,
                                               nullptr, nullptr, 0, out2,
                                               (long)HW * 32, H, W);
    // out3 = conv(out2, ff_w) + frame[:,1]  -> o3rec lower half (record 64)
    conv3x3_cl<32, 32, 32, 1, false, 1, 64, 32, false, 0, 32>
        <<<dim3(256, B, 1), cblk, 0, stream>>>(out2, (long)HW * 32, wff, ff_b,
                                               nullptr, frame + 32L * HW, 96L * HW,
                                               o3rec, (long)HW * 64, H, W);
    // ffn = lrelu(conv_dil2(o3rec[out3|src1], ffn1))
    conv3x3_cl<64, 64, 32, 2, true, 0, 32, 32, false, 0, 32>
        <<<dim3(256, B, 1), cblk, 0, stream>>>(o3rec, (long)HW * 64, wffn1, ffn1_b,
                                               nullptr, nullptr, 0, ffnb,
                                               (long)HW * 32, H, W);
    // out4 = out3 + conv(ffn, ffn2)   (resid = o3rec CL stride 64)
    conv3x3_cl<32, 32, 32, 1, false, 3, 32, 32, false, 64, 32>
        <<<dim3(256, B, 1), cblk, 0, stream>>>(ffnb, (long)HW * 32, wffn2, ffn2_b,
                                               nullptr, o3rec, 0, out4,
                                               (long)HW * 32, H, W);
    // d_out = lrelu(conv1x1(out4, fus))
    conv1x1_f16<<<dim3(HW / 256, B), blk, 0, stream>>>(out4, fus_w, fus_b,
                                                       (float*)d_out, HW);
}